// Round 5
// baseline (154.386 us; speedup 1.0000x reference)
//
#include <hip/hip_runtime.h>

#define N_CLS 8192
#define DIMB  1024          // bytes per row (fp4: 0.5 B/elem, 2048 elems)
#define NBT   32            // 8192/256
#define NFULL 512           // full 256x256 tiles in launch 1
#define NSL   32            // 32 K-slices of 64 elems (32B) each

typedef __attribute__((ext_vector_type(16))) float f32x16;
typedef __attribute__((ext_vector_type(8)))  int   i32x8;

// ---- e2m1 encode: nearest of {0,.5,1,1.5,2,3,4,6} with sign ----
__device__ __forceinline__ unsigned enc1(float v, float sc) {
    float a = fabsf(v) * sc;
    unsigned c = (a >= 0.25f) + (a >= 0.75f) + (a >= 1.25f) + (a >= 1.75f) +
                 (a >= 2.5f)  + (a >= 3.5f)  + (a >= 5.0f);
    return c | ((__float_as_uint(v) >> 28) & 8u);
}
__device__ __forceinline__ unsigned short enc4(float4 v, float sc) {
    return (unsigned short)(enc1(v.x, sc) | (enc1(v.y, sc) << 4) |
                            (enc1(v.z, sc) << 8) | (enc1(v.w, sc) << 12));
}

// ------- kernel 1: wave-per-row L2-normalize, scale x64, quantize to e2m1 -------
__global__ __launch_bounds__(256) void normalize_rows(const float* __restrict__ x,
                                                      unsigned char* __restrict__ xq) {
    const int wid = threadIdx.x >> 6, lane = threadIdx.x & 63;
    const int row = blockIdx.x * 4 + wid;
    const float4* xr = reinterpret_cast<const float4*>(x + (size_t)row * 2048);
    float4 v[8];
    float s = 0.0f;
#pragma unroll
    for (int k = 0; k < 8; ++k) {
        v[k] = xr[lane + 64 * k];
        s += v[k].x*v[k].x + v[k].y*v[k].y + v[k].z*v[k].z + v[k].w*v[k].w;
    }
#pragma unroll
    for (int off = 32; off > 0; off >>= 1) s += __shfl_down(s, off);
    s = __shfl(s, 0);
    const float sc = 64.0f / fmaxf(sqrtf(s), 1e-12f);
    unsigned short* orow = reinterpret_cast<unsigned short*>(xq + (size_t)row * DIMB);
#pragma unroll
    for (int k = 0; k < 8; ++k) orow[lane + 64 * k] = enc4(v[k], sc);
}

// fp4 operand: 16B live in dwords 0..3; duplicate into upper half (ignored for FMT=fp4)
__device__ __forceinline__ i32x8 op4(int4 d) {
    i32x8 r;
    r[0] = d.x; r[1] = d.y; r[2] = d.z; r[3] = d.w;
    r[4] = d.x; r[5] = d.y; r[6] = d.z; r[7] = d.w;
    return r;
}
#define MFMA4(A, B, C) __builtin_amdgcn_mfma_scale_f32_32x32x64_f8f6f4( \
    (A), (B), (C), 4, 4, 0, 0x7F7F7F7F, 0, 0x7F7F7F7F)

// ---- kernel 2: LDS-free register-streamed 256xBN MX-fp4 gram tile + fused exp-sum ----
// NFR=2: 256x256 tiles (blocks 0..511). NFR=1: 256x128 half-tiles of tiles 512..527.
template <int NFR>
__global__ __launch_bounds__(512) void gram_tile(const char* __restrict__ xq,
                                                 float* __restrict__ partials) {
    constexpr int WN = NFR * 32;
    __shared__ float red[8];

    int lin, colHalf;
    if constexpr (NFR == 2) { lin = blockIdx.x; colHalf = 0; }
    else { lin = NFULL + (blockIdx.x >> 1); colHalf = blockIdx.x & 1; }
    int bi = 0, rem = lin;
    while (rem >= NBT - bi) { rem -= NBT - bi; ++bi; }
    const int bj = bi + rem;

    const int tid = threadIdx.x;
    const int lane = tid & 63, wid = tid >> 6;
    const int wr = wid >> 2, wc = wid & 3;     // wave grid 2 x 4
    const int lr = lane & 31, hi = lane >> 5;

    // fragment bases: lane (lr,hi) of fragment (m|n, slice s) reads 16B at
    //   row = tile_base + m*32 + lr ; byte = s*32 + hi*16   (s*32 folds into imm offset)
    const char* aBase = xq + (size_t)(bi * 256 + wr * 128 + lr) * DIMB + hi * 16;
    const char* bBase = xq + (size_t)(bj * 256 + colHalf * 128 + wc * WN + lr) * DIMB + hi * 16;

    f32x16 acc[4][NFR];
#pragma unroll
    for (int m = 0; m < 4; ++m)
#pragma unroll
        for (int n = 0; n < NFR; ++n)
#pragma unroll
            for (int r = 0; r < 16; ++r) acc[m][n][r] = 0.0f;

    int4 aF[3][4], bF[3][NFR];
    // prologue: slices 0,1 into buffers 0,1
#pragma unroll
    for (int s = 0; s < 2; ++s) {
#pragma unroll
        for (int m = 0; m < 4; ++m)
            aF[s][m] = *reinterpret_cast<const int4*>(aBase + (size_t)m * 32 * DIMB + s * 32);
#pragma unroll
        for (int n = 0; n < NFR; ++n)
            bF[s][n] = *reinterpret_cast<const int4*>(bBase + (size_t)n * 32 * DIMB + s * 32);
    }

#pragma unroll
    for (int s = 0; s < NSL; ++s) {
        if ((s & 3) == 0 && s) {               // K-tile boundary: keep waves phase-aligned
            __builtin_amdgcn_sched_barrier(0); // bound scheduler motion / register pressure
            __builtin_amdgcn_s_barrier();
        }
        if (s + 2 < NSL) {                     // prefetch slice s+2 (distance 2)
            const int pb = (s + 2) % 3;
#pragma unroll
            for (int m = 0; m < 4; ++m)
                aF[pb][m] = *reinterpret_cast<const int4*>(aBase + (size_t)m * 32 * DIMB + (s + 2) * 32);
#pragma unroll
            for (int n = 0; n < NFR; ++n)
                bF[pb][n] = *reinterpret_cast<const int4*>(bBase + (size_t)n * 32 * DIMB + (s + 2) * 32);
        }
        const int cb = s % 3;
        __builtin_amdgcn_s_setprio(1);
#pragma unroll
        for (int m = 0; m < 4; ++m)
#pragma unroll
            for (int n = 0; n < NFR; ++n)
                acc[m][n] = MFMA4(op4(aF[cb][m]), op4(bF[cb][n]), acc[m][n]);
        __builtin_amdgcn_s_setprio(0);
    }

    // ---- epilogue: raw dot = 4096*g (scale 64^2); exp(-max(2-2g,0)) = exp(min(raw/2048-2,0)) ----
    float s = 0.0f;
#pragma unroll
    for (int m = 0; m < 4; ++m)
#pragma unroll
        for (int n = 0; n < NFR; ++n)
#pragma unroll
            for (int r = 0; r < 16; ++r)
                s += __expf(fminf(acc[m][n][r] * (1.0f / 2048.0f) - 2.0f, 0.0f));
#pragma unroll
    for (int off = 32; off > 0; off >>= 1) s += __shfl_down(s, off);
    if (lane == 0) red[wid] = s;
    __syncthreads();
    if (tid == 0) {
        float tot = 0.0f;
#pragma unroll
        for (int w = 0; w < 8; ++w) tot += red[w];
        partials[blockIdx.x] = (bi == bj ? 1.0f : 2.0f) * tot;
    }
}

// ---------------- kernel 3: reduce partials, scale ----------------
__global__ __launch_bounds__(256) void finalize(const float* __restrict__ partials,
                                                float* __restrict__ out) {
    float s = 0.f;
    for (int i = threadIdx.x; i < NFULL + 32; i += 256) s += partials[i];
#pragma unroll
    for (int off = 32; off > 0; off >>= 1) s += __shfl_down(s, off);
    __shared__ float red[4];
    if ((threadIdx.x & 63) == 0) red[threadIdx.x >> 6] = s;
    __syncthreads();
    if (threadIdx.x == 0)
        out[0] = (red[0] + red[1] + red[2] + red[3]) *
                 (1.0f / (8191.0f * 8192.0f));
}

extern "C" void kernel_launch(void* const* d_in, const int* in_sizes, int n_in,
                              void* d_out, int out_size, void* d_ws, size_t ws_size,
                              hipStream_t stream) {
    const float* x = (const float*)d_in[0];
    float* out = (float*)d_out;
    unsigned char* xq = (unsigned char*)d_ws;                // 8 MB fp4 matrix
    float* partials = (float*)((char*)d_ws + (size_t)N_CLS * DIMB);

    normalize_rows<<<N_CLS / 4, 256, 0, stream>>>(x, xq);
    gram_tile<2><<<NFULL, 512, 0, stream>>>((const char*)xq, partials);
    gram_tile<1><<<32, 512, 0, stream>>>((const char*)xq, partials + NFULL);
    finalize<<<1, 256, 0, stream>>>(partials, out);
}

// Round 6
// 69.205 us; speedup vs baseline: 2.2308x; 2.2308x over previous
//
#include <hip/hip_runtime.h>

#define N_CLS 8192
#define DIMB  1024          // bytes per row (fp4: 0.5 B/elem, 2048 elems)
#define BKB   128           // K-tile bytes per row = 256 elements
#define NBT   32            // 8192/256
#define NFULL 512           // full 256x256 tiles; +32 half-tile blocks merged
#define NT    8             // DIMB/BKB K-tiles

typedef __attribute__((ext_vector_type(16))) float f32x16;
typedef __attribute__((ext_vector_type(8)))  int   i32x8;

__device__ __forceinline__ void load16(const char* g, char* l) {
    __builtin_amdgcn_global_load_lds(
        (const __attribute__((address_space(1))) void*)g,
        (__attribute__((address_space(3))) void*)l, 16, 0, 0);
}
__device__ __forceinline__ void vm0() {
    asm volatile("s_waitcnt vmcnt(0)" ::: "memory");
}
__device__ __forceinline__ void hard_barrier() {
    __builtin_amdgcn_sched_barrier(0);
    __builtin_amdgcn_s_barrier();
    __builtin_amdgcn_sched_barrier(0);
}

// ---- e2m1 encode: nearest of {0,.5,1,1.5,2,3,4,6} with sign ----
__device__ __forceinline__ unsigned enc1(float v, float sc) {
    float a = fabsf(v) * sc;
    unsigned c = (a >= 0.25f) + (a >= 0.75f) + (a >= 1.25f) + (a >= 1.75f) +
                 (a >= 2.5f)  + (a >= 3.5f)  + (a >= 5.0f);
    return c | ((__float_as_uint(v) >> 28) & 8u);
}
__device__ __forceinline__ unsigned short enc4(float4 v, float sc) {
    return (unsigned short)(enc1(v.x, sc) | (enc1(v.y, sc) << 4) |
                            (enc1(v.z, sc) << 8) | (enc1(v.w, sc) << 12));
}

// ------- kernel 1: wave-per-row L2-normalize, scale x64, quantize to e2m1 -------
__global__ __launch_bounds__(256) void normalize_rows(const float* __restrict__ x,
                                                      unsigned char* __restrict__ xq) {
    const int wid = threadIdx.x >> 6, lane = threadIdx.x & 63;
    const int row = blockIdx.x * 4 + wid;
    const float4* xr = reinterpret_cast<const float4*>(x + (size_t)row * 2048);
    float4 v[8];
    float s = 0.0f;
#pragma unroll
    for (int k = 0; k < 8; ++k) {
        v[k] = xr[lane + 64 * k];
        s += v[k].x*v[k].x + v[k].y*v[k].y + v[k].z*v[k].z + v[k].w*v[k].w;
    }
#pragma unroll
    for (int off = 32; off > 0; off >>= 1) s += __shfl_down(s, off);
    s = __shfl(s, 0);
    const float sc = 64.0f / fmaxf(sqrtf(s), 1e-12f);
    unsigned short* orow = reinterpret_cast<unsigned short*>(xq + (size_t)row * DIMB);
#pragma unroll
    for (int k = 0; k < 8; ++k) orow[lane + 64 * k] = enc4(v[k], sc);
}

// read one 16-byte (K=64, fp4) fragment from a swizzled LDS row; dup into both halves
__device__ __forceinline__ i32x8 rdfrag4(const char* rowp, int cc, int swz) {
    int4 d = *reinterpret_cast<const int4*>(rowp + (((cc) ^ swz) << 4));
    i32x8 r;
    r[0] = d.x; r[1] = d.y; r[2] = d.z; r[3] = d.w;
    r[4] = d.x; r[5] = d.y; r[6] = d.z; r[7] = d.w;
    return r;
}

#define MFMA4(A, B, C) __builtin_amdgcn_mfma_scale_f32_32x32x64_f8f6f4( \
    (A), (B), (C), 4, 4, 0, 0x7F7F7F7F, 0, 0x7F7F7F7F)

// ---- gram body: 4 slice-phases per K-tile, distance-1 staging into opposite slot,
//      single vmcnt(0)+barrier per K-tile (nearly satisfied at arrival) ----
template <int NFR>   // NFR=2: 256x256 tile; NFR=1: 256x128 half-tile
__device__ __forceinline__ void gram_body(const char* __restrict__ xq,
                                          float* __restrict__ partials,
                                          char* As, char* Bs, float* red,
                                          int lin, int colHalf) {
    constexpr int WN     = NFR * 32;
    constexpr int A_SLOT = 256 * BKB;          // 32 KiB
    constexpr int B_SLOT = 256 * BKB;          // fixed stride (NFR=1 uses half)

    int bi = 0, rem = lin;
    while (rem >= NBT - bi) { rem -= NBT - bi; ++bi; }
    const int bj = bi + rem;

    const int tid = threadIdx.x;
    const int lane = tid & 63, wid = tid >> 6;
    const int wr = wid >> 2, wc = wid & 3;     // wave grid 2 x 4

    // staging (pre-swizzled global source; linear LDS dest)
    const int srow = lane >> 3;                      // 0..7 within an 8-row call
    const int gch  = ((lane & 7) ^ srow) << 4;       // involutive 16B-chunk XOR
    const char* gA = xq + (size_t)(bi * 256 + wid * 32 + srow) * DIMB + gch;
    const char* gB = xq + (size_t)(bj * 256 + colHalf * 128 +
                                   wid * (NFR == 2 ? 32 : 16) + srow) * DIMB + gch;

    auto stageA = [&](int tt, int s) {
#pragma unroll
        for (int q = 0; q < 4; ++q)
            load16(gA + (size_t)(q * 8) * DIMB + tt * BKB,
                   &As[s * A_SLOT + wid * 4096 + q * 1024]);
    };
    auto stageB = [&](int tt, int s) {
#pragma unroll
        for (int q = 0; q < 2 * NFR; ++q)
            load16(gB + (size_t)(q * 8) * DIMB + tt * BKB,
                   &Bs[s * B_SLOT + wid * (2 * NFR * 1024) + q * 1024]);
    };

    const int lr = lane & 31, hi = lane >> 5, swz = lane & 7;

    f32x16 acc[4][NFR];
#pragma unroll
    for (int m = 0; m < 4; ++m)
#pragma unroll
        for (int n = 0; n < NFR; ++n)
#pragma unroll
            for (int r = 0; r < 16; ++r) acc[m][n][r] = 0.0f;

    // prologue: stage tile 0 only; tile 1 staged during iteration 0
    stageA(0, 0); stageB(0, 0);
    vm0();
    hard_barrier();

    for (int t = 0; t < NT; ++t) {
        const char* arow = &As[(t & 1) * A_SLOT] + (wr * 128 + lr) * BKB;
        const char* brow = &Bs[(t & 1) * B_SLOT] + (wc * WN + lr) * BKB;
        const int ns = (t & 1) ^ 1;                // opposite slot for t+1
#pragma unroll
        for (int s = 0; s < 4; ++s) {
            i32x8 af[4], bf[NFR];
#pragma unroll
            for (int m = 0; m < 4; ++m)
                af[m] = rdfrag4(arow + m * 32 * BKB, 2 * s + hi, swz);
#pragma unroll
            for (int n = 0; n < NFR; ++n)
                bf[n] = rdfrag4(brow + n * 32 * BKB, 2 * s + hi, swz);
            if (t + 1 < NT) {                      // stage next tile early (phases 0,1)
                if (s == 0) stageA(t + 1, ns);
                if (s == 1) stageB(t + 1, ns);
            }
            __builtin_amdgcn_s_setprio(1);
#pragma unroll
            for (int m = 0; m < 4; ++m)
#pragma unroll
                for (int n = 0; n < NFR; ++n)
                    acc[m][n] = MFMA4(af[m], bf[n], acc[m][n]);
            __builtin_amdgcn_s_setprio(0);
            __builtin_amdgcn_sched_barrier(0);     // bound VGPR / keep phase shape
        }
        if (t < NT - 1) {
            vm0();                                 // t+1's stages issued >=2 phases ago
            hard_barrier();
        }
    }

    // epilogue: raw dot = 4096*g (scale 64^2); exp(-max(2-2g,0)) = exp(min(raw/2048-2,0))
    float s = 0.0f;
#pragma unroll
    for (int m = 0; m < 4; ++m)
#pragma unroll
        for (int n = 0; n < NFR; ++n)
#pragma unroll
            for (int r = 0; r < 16; ++r)
                s += __expf(fminf(acc[m][n][r] * (1.0f / 2048.0f) - 2.0f, 0.0f));
#pragma unroll
    for (int off = 32; off > 0; off >>= 1) s += __shfl_down(s, off);
    if (lane == 0) red[wid] = s;
    __syncthreads();
    if (tid == 0) {
        float tot = 0.0f;
#pragma unroll
        for (int w = 0; w < 8; ++w) tot += red[w];
        partials[blockIdx.x] = (bi == bj ? 1.0f : 2.0f) * tot;
    }
}

// merged launch: blocks 0..511 full tiles, 512..543 half-tiles (backfill the makespan tail)
__global__ __launch_bounds__(512, 2) void gram_tile(const char* __restrict__ xq,
                                                    float* __restrict__ partials) {
    __shared__ __align__(16) char As[2 * 256 * BKB];   // 64 KiB
    __shared__ __align__(16) char Bs[2 * 256 * BKB];   // 64 KiB
    __shared__ float red[8];
    if (blockIdx.x < NFULL)
        gram_body<2>(xq, partials, As, Bs, red, blockIdx.x, 0);
    else
        gram_body<1>(xq, partials, As, Bs, red,
                     NFULL + ((blockIdx.x - NFULL) >> 1), (blockIdx.x - NFULL) & 1);
}

// ---------------- kernel 3: reduce partials, scale ----------------
__global__ __launch_bounds__(256) void finalize(const float* __restrict__ partials,
                                                float* __restrict__ out) {
    float s = 0.f;
    for (int i = threadIdx.x; i < NFULL + 32; i += 256) s += partials[i];
#pragma unroll
    for (int off = 32; off > 0; off >>= 1) s += __shfl_down(s, off);
    __shared__ float red[4];
    if ((threadIdx.x & 63) == 0) red[threadIdx.x >> 6] = s;
    __syncthreads();
    if (threadIdx.x == 0)
        out[0] = (red[0] + red[1] + red[2] + red[3]) *
                 (1.0f / (8191.0f * 8192.0f));
}

extern "C" void kernel_launch(void* const* d_in, const int* in_sizes, int n_in,
                              void* d_out, int out_size, void* d_ws, size_t ws_size,
                              hipStream_t stream) {
    const float* x = (const float*)d_in[0];
    float* out = (float*)d_out;
    unsigned char* xq = (unsigned char*)d_ws;                // 8 MB fp4 matrix
    float* partials = (float*)((char*)d_ws + (size_t)N_CLS * DIMB);

    normalize_rows<<<N_CLS / 4, 256, 0, stream>>>(x, xq);
    gram_tile<<<NFULL + 32, 512, 0, stream>>>((const char*)xq, partials);
    finalize<<<1, 256, 0, stream>>>(partials, out);
}